// Round 3
// baseline (3766.064 us; speedup 1.0000x reference)
//
#include <hip/hip_runtime.h>
#include <stdint.h>

// ---------------------------------------------------------------------------
// LSTM_14242111554073  (B=32, S=512, IN=512, H=1024, fp32 in/out)
// Phase 1: gx = x @ [wxf|wxi|wxo|wxc]  (bf16 MFMA GEMM, 16384x512x4096)
// Phase 2: persistent scan, 128 WGs (1/CU), gate-interleaved columns:
//   WG w owns h-cols j0=w*8..j0+7; gate-col order j' = jj*4+g so each lane's
//   4 MFMA C-regs are the f,i,o,c gates of one (b,jj) -> lane-local epilogue,
//   no LDS reduce, no barriers B. MFMA: m=32 gate-cols (A=Wh^T in LDS),
//   n=32 batch (B=h_t from LLC), K=1024; each wave one 16x16 tile, full K.
//   Sync: 8 per-step LLC counters (counter c = producers of k-chunk c);
//   waves poll chunk-by-chunk and issue that chunk's B-frag loads right away.
// ---------------------------------------------------------------------------

typedef short bf16x8 __attribute__((ext_vector_type(8)));
typedef float f32x4  __attribute__((ext_vector_type(4)));

#define MFMA16(a, b, c) __builtin_amdgcn_mfma_f32_16x16x32_bf16((a), (b), (c), 0, 0, 0)

__device__ __forceinline__ unsigned short f2bf(float f) {
    unsigned int u = __builtin_bit_cast(unsigned int, f);
    u = (u + 0x7FFFu + ((u >> 16) & 1u)) >> 16;   // RNE
    return (unsigned short)u;
}
__device__ __forceinline__ float bf2f(unsigned short h) {
    unsigned int u = ((unsigned int)h) << 16;
    return __builtin_bit_cast(float, u);
}
__device__ __forceinline__ float sigmoidf_(float x) { return 1.0f / (1.0f + __expf(-x)); }
__device__ __forceinline__ float tanhf_(float x)    { return 1.0f - 2.0f / (__expf(2.0f * x) + 1.0f); }

// ---------------------------------------------------------------------------
// Kernel 1: gx GEMM (unchanged this round — scan dominates).
// ---------------------------------------------------------------------------
__global__ void __launch_bounds__(256) gx_gemm(
    const float* __restrict__ X,
    const float* __restrict__ Wf, const float* __restrict__ Wi,
    const float* __restrict__ Wo, const float* __restrict__ Wc,
    unsigned short* __restrict__ gxOut)
{
    __shared__ unsigned short As[128 * 40];
    __shared__ unsigned short Bs[128 * 40];

    const int tid  = threadIdx.x;
    const int lane = tid & 63;
    const int wid  = tid >> 6;
    const int lr   = lane & 15;
    const int lq   = lane >> 4;

    const int m0 = blockIdx.x * 128;
    const int n0 = blockIdx.y * 128;
    const float* Wg = (n0 < 1024) ? Wf : (n0 < 2048) ? Wi : (n0 < 3072) ? Wo : Wc;
    const int ncol0 = n0 & 1023;

    const int mw = (wid & 1) * 64;
    const int nw = (wid >> 1) * 64;

    f32x4 acc[4][4];
#pragma unroll
    for (int i = 0; i < 4; i++)
#pragma unroll
        for (int j = 0; j < 4; j++) acc[i][j] = (f32x4){0.f, 0.f, 0.f, 0.f};

    for (int k0 = 0; k0 < 512; k0 += 32) {
#pragma unroll
        for (int i = 0; i < 4; i++) {
            int s   = tid + i * 256;
            int row = s >> 3;
            int c4  = s & 7;
            float4 v = *(const float4*)(X + (size_t)(m0 + row) * 512 + k0 + c4 * 4);
            ushort4 h;
            h.x = f2bf(v.x); h.y = f2bf(v.y); h.z = f2bf(v.z); h.w = f2bf(v.w);
            *(ushort4*)(As + row * 40 + c4 * 4) = h;
        }
#pragma unroll
        for (int i = 0; i < 4; i++) {
            int s  = tid + i * 256;
            int kk = s >> 5;
            int c4 = s & 31;
            float4 v = *(const float4*)(Wg + (size_t)(k0 + kk) * 1024 + ncol0 + c4 * 4);
            Bs[(c4 * 4 + 0) * 40 + kk] = f2bf(v.x);
            Bs[(c4 * 4 + 1) * 40 + kk] = f2bf(v.y);
            Bs[(c4 * 4 + 2) * 40 + kk] = f2bf(v.z);
            Bs[(c4 * 4 + 3) * 40 + kk] = f2bf(v.w);
        }
        __syncthreads();

        bf16x8 af[4], bfr[4];
#pragma unroll
        for (int tm = 0; tm < 4; tm++)
            af[tm] = *(const bf16x8*)(As + (mw + tm * 16 + lr) * 40 + lq * 8);
#pragma unroll
        for (int tn = 0; tn < 4; tn++)
            bfr[tn] = *(const bf16x8*)(Bs + (nw + tn * 16 + lr) * 40 + lq * 8);
#pragma unroll
        for (int tm = 0; tm < 4; tm++)
#pragma unroll
            for (int tn = 0; tn < 4; tn++)
                acc[tm][tn] = MFMA16(af[tm], bfr[tn], acc[tm][tn]);
        __syncthreads();
    }

#pragma unroll
    for (int tm = 0; tm < 4; tm++)
#pragma unroll
        for (int tn = 0; tn < 4; tn++)
#pragma unroll
            for (int r = 0; r < 4; r++) {
                int row = m0 + mw + tm * 16 + lq * 4 + r;
                int col = n0 + nw + tn * 16 + lr;
                gxOut[(size_t)row * 4096 + col] = f2bf(acc[tm][tn][r]);
            }
}

// ---------------------------------------------------------------------------
// Kernel 2: persistent scan. LDS: Wlds [32 j'][1032 k] bf16 = 66048 B only.
// ---------------------------------------------------------------------------
#define NWG 128
#define NCNT 8
#define LDS2_BYTES 66048

__global__ void __launch_bounds__(256, 1) lstm_scan(
    const float* __restrict__ Whf, const float* __restrict__ Whi,
    const float* __restrict__ Who, const float* __restrict__ Whc,
    const float* __restrict__ Bf,  const float* __restrict__ Bi,
    const float* __restrict__ Bo,  const float* __restrict__ Bc,
    const unsigned short* __restrict__ gx,
    unsigned short* __restrict__ hhist,   // [512][32][1024] bf16, slot t = h_t
    unsigned int* __restrict__ flags,     // [512][NCNT]; flags[t][c]==16 => k-chunk c of h_t ready
    float* __restrict__ out)
{
    extern __shared__ char lds[];
    unsigned short* Wlds = (unsigned short*)lds;   // [j'=jj*4+g][k], stride 1032

    const int tid  = threadIdx.x;
    const int w    = blockIdx.x;
    const int j0   = w * 8;
    const int lane = tid & 63;
    const int wid  = tid >> 6;
    const int lr   = lane & 15;
    const int lq   = lane >> 4;
    const int mt   = wid & 1;        // gate-col tile: jj range [mt*4, mt*4+4)
    const int nt   = wid >> 1;       // batch tile:    b  range [nt*16, nt*16+16)

    const int b  = nt * 16 + lr;     // this lane's batch row (C/D col)
    const int jj = mt * 4 + lq;      // this lane's h-col within slice (C/D row group)
    const int jg = j0 + jj;          // global h-col

    // ---- Wh slice -> LDS, gate-interleaved rows j' = jj*4 + g ----
#pragma unroll 4
    for (int i = 0; i < 128; i++) {
        int e = i * 256 + tid;       // 0..32767
        int k = e >> 5;
        int c = e & 31;              // j'
        int g = c & 3, j = c >> 2;
        const float* wp = (g == 0) ? Whf : (g == 1) ? Whi : (g == 2) ? Who : Whc;
        Wlds[c * 1032 + k] = f2bf(wp[(size_t)k * 1024 + j0 + j]);
    }

    // ---- per-lane biases (f,i,o,c of column jg) ----
    const float bsf = Bf[jg], bsi = Bi[jg], bso = Bo[jg], bsc = Bc[jg];

    float c_reg = 0.f;

    // ---- gx prefetch for t=0 ----
    const unsigned short* gxp = gx + (size_t)b * 512 * 4096 + jg;
    unsigned short gxv0 = gxp[0], gxv1 = gxp[1024], gxv2 = gxp[2048], gxv3 = gxp[3072];

    __syncthreads();

    const unsigned short* abase = Wlds + (mt * 16 + lr) * 1032 + lq * 8;

    for (int t = 0; t < 512; t++) {
        f32x4 accf = (f32x4){0.f, 0.f, 0.f, 0.f};

        if (t > 0) {
            // ---- poll per k-chunk, issue that chunk's B-frags immediately ----
            const unsigned int* fp = flags + (size_t)t * NCNT;
            const unsigned short* hb = hhist + (size_t)t * 32768 + (size_t)b * 1024 + lq * 8;
            bf16x8 bfB[32];
#pragma unroll
            for (int c = 0; c < 8; c++) {
                while (__hip_atomic_load(fp + c, __ATOMIC_RELAXED, __HIP_MEMORY_SCOPE_AGENT) != 16u) {}
                asm volatile("" ::: "memory");   // no hoisting data loads above the spin
#pragma unroll
                for (int s = 0; s < 4; s++)
                    bfB[c * 4 + s] = *(const bf16x8*)(hb + c * 128 + s * 32);
            }
            // ---- MFMA: one 16x16 tile, K=1024, 4 interleaved acc chains ----
            f32x4 acc[4];
#pragma unroll
            for (int a = 0; a < 4; a++) acc[a] = (f32x4){0.f, 0.f, 0.f, 0.f};
#pragma unroll
            for (int c = 0; c < 8; c++)
#pragma unroll
                for (int s = 0; s < 4; s++) {
                    bf16x8 af = *(const bf16x8*)(abase + c * 128 + s * 32);
                    acc[s] = MFMA16(af, bfB[c * 4 + s], acc[s]);
                }
            accf = (acc[0] + acc[1]) + (acc[2] + acc[3]);
        }

        // ---- lane-local epilogue: regs r=0..3 are f,i,o,c of (b, jj) ----
        float fg = sigmoidf_(accf[0] + bf2f(gxv0) + bsf);
        float ig = sigmoidf_(accf[1] + bf2f(gxv1) + bsi);
        float og = sigmoidf_(accf[2] + bf2f(gxv2) + bso);
        float cg = sigmoidf_(accf[3] + bf2f(gxv3) + bsc);
        float cn = fg * c_reg + ig * cg;
        c_reg = cn;
        float hn = og * tanhf_(cn);

        if (t < 511) {
            // ---- h_{t+1}: pack (jj even | jj odd) into dword, store to LLC ----
            unsigned int hb16 = (unsigned int)f2bf(hn);
            unsigned int ot16 = (unsigned int)__shfl_xor((int)hb16, 16);  // jj^1 partner
            if ((lq & 1) == 0) {
                unsigned int v = (hb16 & 0xFFFFu) | (ot16 << 16);
                unsigned int* dst = (unsigned int*)(hhist + (size_t)(t + 1) * 32768
                                                    + (size_t)b * 1024 + jg);
                __hip_atomic_store(dst, v, __ATOMIC_RELAXED, __HIP_MEMORY_SCOPE_AGENT);
            }
            asm volatile("s_waitcnt vmcnt(0)" ::: "memory");  // h at LLC
            __syncthreads();                                   // all 4 waves drained
            if (tid == 0)
                atomicAdd(flags + (size_t)(t + 1) * NCNT + (w >> 4), 1u);
            // ---- off-critical-path stores & next-step prefetch ----
            out[((size_t)b * 512 + t) * 1024 + jg] = og;
            const unsigned short* gq = gxp + (size_t)(t + 1) * 4096;
            gxv0 = gq[0]; gxv1 = gq[1024]; gxv2 = gq[2048]; gxv3 = gq[3072];
        } else {
            out[((size_t)b * 512 + t) * 1024 + jg] = og;
            out[16777216 + (size_t)b * 1024 + jg]          = hn;   // ht
            out[16777216 + 32768 + (size_t)b * 1024 + jg]  = cn;   // ct
        }
    }
}

__global__ void ws_diag(float* out, float mb) { out[threadIdx.x] = -mb; }

extern "C" void kernel_launch(void* const* d_in, const int* in_sizes, int n_in,
                              void* d_out, int out_size, void* d_ws, size_t ws_size,
                              hipStream_t stream)
{
    const float* x   = (const float*)d_in[0];
    const float* wxf = (const float*)d_in[1];
    const float* whf = (const float*)d_in[2];
    const float* bhf = (const float*)d_in[3];
    const float* wxi = (const float*)d_in[4];
    const float* whi = (const float*)d_in[5];
    const float* bhi = (const float*)d_in[6];
    const float* wxo = (const float*)d_in[7];
    const float* who = (const float*)d_in[8];
    const float* bho = (const float*)d_in[9];
    const float* wxc = (const float*)d_in[10];
    const float* whc = (const float*)d_in[11];
    const float* bhc = (const float*)d_in[12];
    float* out = (float*)d_out;

    const size_t GX_BYTES = (size_t)16384 * 4096 * 2;    // 134217728
    const size_t HH_BYTES = (size_t)512 * 32 * 1024 * 2; //  33554432
    const size_t FL_BYTES = (size_t)512 * NCNT * 4;      //     16384
    const size_t NEED = GX_BYTES + HH_BYTES + FL_BYTES;

    if (ws_size < NEED) {
        ws_diag<<<dim3(1), dim3(256), 0, stream>>>(out, (float)(ws_size >> 20));
        return;
    }

    unsigned short* gxbuf = (unsigned short*)d_ws;
    unsigned short* hh    = (unsigned short*)((char*)d_ws + GX_BYTES);
    unsigned int*   flags = (unsigned int*)((char*)d_ws + GX_BYTES + HH_BYTES);

    (void)hipFuncSetAttribute((const void*)lstm_scan,
                              hipFuncAttributeMaxDynamicSharedMemorySize, LDS2_BYTES);

    gx_gemm<<<dim3(128, 32), dim3(256), 0, stream>>>(x, wxf, wxi, wxo, wxc, gxbuf);
    hipMemsetAsync(flags, 0, FL_BYTES, stream);
    lstm_scan<<<dim3(NWG), dim3(256), LDS2_BYTES, stream>>>(
        whf, whi, who, whc, bhf, bhi, bho, bhc, gxbuf, hh, flags, out);
}